// Round 4
// baseline (637.470 us; speedup 1.0000x reference)
//
#include <hip/hip_runtime.h>

#define HH  512
#define WW  512
#define HPP 64
#define WPP 2048
#define BB  4
#define CC  64

// Fill the center "drop" disk (pixels the scatter never writes) from ref_feat.
// The disk (depth <= ~16.22px around center 255.5) fits in rows/cols 240..271.
__global__ __launch_bounds__(256) void fill_disk(
    const float* __restrict__ ref, float* __restrict__ out) {
    int t  = blockIdx.x * 256 + threadIdx.x;   // 0..1023 -> 32x32 box
    int bc = blockIdx.y;                       // 0..255 = b*C+c plane
    int r = 240 + (t >> 5);
    int c = 240 + (t & 31);
    float yyc = (float)r - 255.5f;
    float xxc = (float)c - 255.5f;
    float depth = sqrtf(yyc * yyc + xxc * xxc);
    float iyv = depth * (67.0f / 362.03867196751236f) - 3.0f;
    if (iyv <= 1e-3f) {
        size_t off = (size_t)bc * (HH * WW) + (size_t)r * WW + c;
        out[off] = ref[off];
    }
}

// Scatter (gx,gy) into a pixel-indexed map. Map pre-filled with 0xFF (= NaN);
// NaN fails (x > -2), so never-scattered (disk) pixels are skipped.
__global__ __launch_bounds__(256) void scatter_map(
    const float* __restrict__ gx, const float* __restrict__ gy,
    const int* __restrict__ idx_y, const int* __restrict__ idx_x,
    float2* __restrict__ map, int N) {
    int n = blockIdx.x * 256 + threadIdx.x;
    if (n >= N) return;
    map[idx_y[n] * WW + idx_x[n]] = make_float2(gx[n], gy[n]);
}

struct __attribute__((packed, aligned(4))) fpair { float lo, hi; };

// v4: LDS-staged bilinear sample.
// v2/v3 were TA transaction-bound: ~40 cyc per VMEM instr, invariant to
// occupancy (71%->37% with no slowdown) and to tile shape. Each pair-gather
// touches ~10 distinct 64B lines; total ~25M line-touches ~= 205us at the
// observed ~5cy/line TA rate. Fix: touch each polar line ONCE per block.
// Per 16x16 cart tile: reduce the polar bbox of the tile's taps; per channel,
// stage bbox (<=8 rows x <=128 cols) into LDS with coalesced loads, then all
// 256 px sample from LDS (idle pipe; +1-pad stride -> no conflicts).
// Fallback (bbox too wide: center ring r<~60 and phi-seam tiles, ~8% of
// blocks): v3's verified per-pixel gather path, block-uniform branch.
__global__ __launch_bounds__(256) void sample_tiled_lds(
    const float* __restrict__ polar, const float2* __restrict__ map,
    float* __restrict__ out) {
    __shared__ float sbuf[8 * 129];      // staged bbox, stride 129 (pad +1)
    __shared__ int   red[4][4];          // per-wave {minx,maxx,miny,maxy}

    // bijective XCD swizzle over 1024 tiles (1024 % 8 == 0)
    int bid = blockIdx.x;
    int swz = ((bid & 7) << 7) + (bid >> 3);
    int tile_r = swz >> 5, tile_c = swz & 31;   // 32x32 tiles of 16x16 px

    int t = (int)threadIdx.x;
    int wave = t >> 6;
    int pr = t >> 4, pc = t & 15;               // pixel within tile (row-major)
    int r = tile_r * 16 + pr, c = tile_c * 16 + pc;

    float2 mv = map[r * WW + c];
    bool valid = (mv.x > -2.0f);                // NaN -> false

    // --- per-pixel tap coords + weights (identical formula to v2/v3) ---
    float ixf = (mv.x + 1.0f) * ((WPP - 1) * 0.5f);
    float iyf = (mv.y + 1.0f) * ((HPP - 1) * 0.5f);
    float x0f = floorf(ixf), y0f = floorf(iyf);
    float wx1 = ixf - x0f,  wy1 = iyf - y0f;
    float wx0 = 1.0f - wx1, wy0 = 1.0f - wy1;
    int x0 = (int)x0f, y0 = (int)y0f;
    int x1 = x0 + 1,   y1 = y0 + 1;
    bool vx0 = (x0 >= 0) & (x0 < WPP);
    bool vx1 = (x1 >= 0) & (x1 < WPP);
    bool vy0 = (y0 >= 0) & (y0 < HPP);
    bool vy1 = (y1 >= 0) & (y1 < HPP);
    float w00 = (vx0 && vy0) ? wx0 * wy0 : 0.0f;
    float w01 = (vx1 && vy0) ? wx1 * wy0 : 0.0f;
    float w10 = (vx0 && vy1) ? wx0 * wy1 : 0.0f;
    float w11 = (vx1 && vy1) ? wx1 * wy1 : 0.0f;

    // --- block-wide bbox reduction over valid pixels ---
    int rxn = valid ? x0 : INT_MAX, rxm = valid ? x0 : INT_MIN;
    int ryn = valid ? y0 : INT_MAX, rym = valid ? y0 : INT_MIN;
    for (int off = 32; off; off >>= 1) {
        rxn = min(rxn, __shfl_xor(rxn, off));
        rxm = max(rxm, __shfl_xor(rxm, off));
        ryn = min(ryn, __shfl_xor(ryn, off));
        rym = max(rym, __shfl_xor(rym, off));
    }
    if ((t & 63) == 0) {
        red[wave][0] = rxn; red[wave][1] = rxm;
        red[wave][2] = ryn; red[wave][3] = rym;
    }
    __syncthreads();
    int xmn = min(min(red[0][0], red[1][0]), min(red[2][0], red[3][0]));
    int xmx = max(max(red[0][1], red[1][1]), max(red[2][1], red[3][1]));
    int ymn = min(min(red[0][2], red[1][2]), min(red[2][2], red[3][2]));
    int ymx = max(max(red[0][3], red[1][3]), max(red[2][3], red[3][3]));
    if (xmn == INT_MAX) return;                 // whole tile unmasked

    int sxmin = xmn, sxmax = min(xmx + 1, WPP - 1);
    int symin = ymn, symax = ymx + 1;           // y0 in [0,62] -> symax <= 63
    int ncols = sxmax - sxmin + 1, nrows = symax - symin + 1;

    int b = blockIdx.y;
    const float* pf = polar + (size_t)b * ((size_t)CC * HPP * WPP);
    char* ob = (char*)out + (size_t)b * ((size_t)CC * HH * WW * 4)
                          + (size_t)(r * WW + c) * 4;

    if (nrows <= 8 && ncols <= 128) {
        // ---- mode A: LDS-staged ----
        int n = nrows * ncols;                  // <= 1024
        int gofs[4], lofs[4], cnt = 0;
        for (int i = t; i < n; i += 256) {      // <=4 iters
            int row = i / ncols, col = i - row * ncols;
            gofs[cnt] = (symin + row) * WPP + sxmin + col;
            lofs[cnt] = row * 129 + col;
            ++cnt;
        }
        int lx0 = 0, lx1 = 0, ly0 = 0, ly1 = 0;
        if (valid) {
            lx0 = x0 - sxmin;                   // x0 >= sxmin by construction
            lx1 = min(lx0 + 1, ncols - 1);      // x1 out of bbox only if w=0
            ly0 = y0 - symin; ly1 = ly0 + 1;
        }
        int a00 = ly0 * 129 + lx0, a01 = ly0 * 129 + lx1;
        int a10 = ly1 * 129 + lx0, a11 = ly1 * 129 + lx1;

        for (int ch = 0; ch < CC; ++ch) {
            __syncthreads();                    // prev sampling done
            float v0, v1, v2, v3;
            if (cnt > 0) v0 = pf[gofs[0]];
            if (cnt > 1) v1 = pf[gofs[1]];
            if (cnt > 2) v2 = pf[gofs[2]];
            if (cnt > 3) v3 = pf[gofs[3]];
            if (cnt > 0) sbuf[lofs[0]] = v0;
            if (cnt > 1) sbuf[lofs[1]] = v1;
            if (cnt > 2) sbuf[lofs[2]] = v2;
            if (cnt > 3) sbuf[lofs[3]] = v3;
            __syncthreads();
            if (valid) {
                float p00 = sbuf[a00], p01 = sbuf[a01];
                float p10 = sbuf[a10], p11 = sbuf[a11];
                float v = p00 * w00 + p01 * w01 + p10 * w10 + p11 * w11;
                *(float*)ob = v;
            }
            pf += HPP * WPP;
            ob += (size_t)HH * WW * 4;
        }
    } else {
        // ---- mode B: per-pixel gather (v3 path) ----
        if (!valid) return;
        int xs  = min(max(x0, 0), WPP - 2);
        int ys0 = min(max(y0, 0), HPP - 1);
        int ys1 = min(max(y1, 0), HPP - 1);
        unsigned offA = (unsigned)(ys0 * WPP + xs) * 4u;
        unsigned offB = (unsigned)(ys1 * WPP + xs) * 4u;
        const char* pb = (const char*)pf;
        #pragma unroll 8
        for (int ch = 0; ch < CC; ++ch) {
            fpair a01 = *(const fpair*)(pb + offA);
            fpair b01 = *(const fpair*)(pb + offB);
            float v = a01.lo * w00 + a01.hi * w01 + b01.lo * w10 + b01.hi * w11;
            *(float*)ob = v;
            pb += (size_t)HPP * WPP * 4;
            ob += (size_t)HH * WW * 4;
        }
    }
}

// ---- v2 fallback (only if ws_size < 2MB): verified at 209us ----
__global__ __launch_bounds__(256) void sample_scatter_v2(
    const float* __restrict__ polar,
    const float* __restrict__ gx, const float* __restrict__ gy,
    const int* __restrict__ idx_y, const int* __restrict__ idx_x,
    float* __restrict__ out, int N) {
    int nwg = gridDim.x;
    int bid = blockIdx.x;
    int q = nwg >> 3, rr = nwg & 7;
    int xcd = bid & 7, lid = bid >> 3;
    int swz = (xcd < rr ? xcd * (q + 1) : rr * (q + 1) + (xcd - rr) * q) + lid;

    int n = swz * 256 + (int)threadIdx.x;
    if (n >= N) return;
    int b = blockIdx.y;

    float gxv = gx[n], gyv = gy[n];
    float ixf = (gxv + 1.0f) * ((WPP - 1) * 0.5f);
    float iyf = (gyv + 1.0f) * ((HPP - 1) * 0.5f);
    float x0f = floorf(ixf), y0f = floorf(iyf);
    float wx1 = ixf - x0f,  wy1 = iyf - y0f;
    float wx0 = 1.0f - wx1, wy0 = 1.0f - wy1;
    int x0 = (int)x0f, y0 = (int)y0f;
    int x1 = x0 + 1,   y1 = y0 + 1;

    bool vx0 = (x0 >= 0) & (x0 < WPP);
    bool vx1 = (x1 >= 0) & (x1 < WPP);
    bool vy0 = (y0 >= 0) & (y0 < HPP);
    bool vy1 = (y1 >= 0) & (y1 < HPP);
    float w00 = (vx0 && vy0) ? wx0 * wy0 : 0.0f;
    float w01 = (vx1 && vy0) ? wx1 * wy0 : 0.0f;
    float w10 = (vx0 && vy1) ? wx0 * wy1 : 0.0f;
    float w11 = (vx1 && vy1) ? wx1 * wy1 : 0.0f;

    int xs  = min(max(x0, 0), WPP - 2);
    int ys0 = min(max(y0, 0), HPP - 1);
    int ys1 = min(max(y1, 0), HPP - 1);

    int oy = idx_y[n], ox = idx_x[n];
    const char* pb = (const char*)polar + (size_t)b * ((size_t)CC * HPP * WPP * 4);
    char*       ob = (char*)out + (size_t)b * ((size_t)CC * HH * WW * 4)
                               + (size_t)(oy * WW + ox) * 4;
    unsigned offA = (unsigned)(ys0 * WPP + xs) * 4u;
    unsigned offB = (unsigned)(ys1 * WPP + xs) * 4u;

    #pragma unroll 8
    for (int ch = 0; ch < CC; ++ch) {
        fpair a01 = *(const fpair*)(pb + offA);
        fpair b01 = *(const fpair*)(pb + offB);
        float v = a01.lo * w00 + a01.hi * w01 + b01.lo * w10 + b01.hi * w11;
        __builtin_nontemporal_store(v, (float*)ob);
        pb += (size_t)HPP * WPP * 4;
        ob += (size_t)HH * WW * 4;
    }
}

extern "C" void kernel_launch(void* const* d_in, const int* in_sizes, int n_in,
                              void* d_out, int out_size, void* d_ws, size_t ws_size,
                              hipStream_t stream) {
    const float* polar = (const float*)d_in[0];
    const float* ref   = (const float*)d_in[1];
    const float* gxp   = (const float*)d_in[2];
    const float* gyp   = (const float*)d_in[3];
    const int*   iyp   = (const int*)d_in[4];
    const int*   ixp   = (const int*)d_in[5];
    float* out = (float*)d_out;
    int N = in_sizes[2];

    const size_t map_bytes = (size_t)HH * WW * sizeof(float2);   // 2 MB

    fill_disk<<<dim3(4, BB * CC), 256, 0, stream>>>(ref, out);

    if (ws_size >= map_bytes) {
        float2* map = (float2*)d_ws;
        hipMemsetAsync(map, 0xFF, map_bytes, stream);
        scatter_map<<<dim3((N + 255) / 256), 256, 0, stream>>>(
            gxp, gyp, iyp, ixp, map, N);
        sample_tiled_lds<<<dim3(1024, BB), 256, 0, stream>>>(polar, map, out);
    } else {
        sample_scatter_v2<<<dim3((N + 255) / 256, BB), 256, 0, stream>>>(
            polar, gxp, gyp, iyp, ixp, out, N);
    }
}